// Round 1
// baseline (180.823 us; speedup 1.0000x reference)
//
#include <hip/hip_runtime.h>
#include <hip/hip_bf16.h>

#define D 128

typedef short bf16x8 __attribute__((ext_vector_type(8)));
typedef float f32x4 __attribute__((ext_vector_type(4)));

__device__ __forceinline__ unsigned short f2bf(float x) {
    __hip_bfloat16 h = __float2bfloat16(x);
    return *reinterpret_cast<unsigned short*>(&h);
}
__device__ __forceinline__ float bf2f(unsigned int lo16bits) {
    return __uint_as_float(lo16bits << 16);
}

// exact-ish GELU: erf via Abramowitz-Stegun 7.1.26 (max abs err 1.5e-7), branchless
__device__ __forceinline__ float gelu_erf(float z) {
    float y = fabsf(z) * 0.70710678118654752f;      // |z|/sqrt(2)
    float t = __builtin_amdgcn_rcpf(1.0f + 0.3275911f * y);
    float poly = ((((1.061405429f * t - 1.453152027f) * t + 1.421413741f) * t
                   - 0.284496736f) * t + 0.254829592f) * t;
    float e = __expf(-y * y);
    float erfv = 1.0f - poly * e;
    erfv = copysignf(erfv, z);
    return 0.5f * z * (1.0f + erfv);
}

// ---------------- K0: Wc = W2 @ Wp, stored transposed WcT[c][k] ----------------
__global__ void wc_kernel(const float* __restrict__ W2, const float* __restrict__ Wp,
                          float* __restrict__ WcT) {
    int idx = blockIdx.x * blockDim.x + threadIdx.x;   // 5 blocks x 128 = 640
    if (idx >= 5 * D) return;
    int c = idx >> 7;
    int k = idx & 127;
    float acc = 0.f;
    #pragma unroll 8
    for (int m = 0; m < D; ++m) acc += W2[k * D + m] * Wp[m * 5 + c];
    WcT[c * D + k] = acc;
}

// ---------------- K1/K2: node transform  out_bf16 = bf16(feat @ W1[base:base+128]) ----------------
__global__ __launch_bounds__(256) void node_kernel(const float* __restrict__ feat,
                                                   const float* __restrict__ W1,
                                                   int base_k, int Nn,
                                                   unsigned short* __restrict__ outbf) {
    // padded leading dim 136 (pad 8 bf16 = 16B) -> conflict-free b128 fragment reads
    __shared__ unsigned short sA[64 * 136];    // sA[row][k]
    __shared__ unsigned short sB[128 * 136];   // sB[j][k] = W1[base_k+k][j] (transposed)
    const int t = threadIdx.x;
    const int r0 = blockIdx.x * 64;

    // stage A tile: 64x128 f32 -> bf16
    #pragma unroll
    for (int i = 0; i < 8; ++i) {
        int f = (i * 256 + t) * 4;
        int row = f >> 7, col = f & 127;
        float4 v = make_float4(0.f, 0.f, 0.f, 0.f);
        if (r0 + row < Nn) v = *reinterpret_cast<const float4*>(&feat[(size_t)(r0 + row) * D + col]);
        unsigned short* p = &sA[row * 136 + col];
        p[0] = f2bf(v.x); p[1] = f2bf(v.y); p[2] = f2bf(v.z); p[3] = f2bf(v.w);
    }
    // stage W half, transposed: 128x128
    #pragma unroll
    for (int i = 0; i < 16; ++i) {
        int f = (i * 256 + t) * 4;
        int k = f >> 7, j = f & 127;
        float4 v = *reinterpret_cast<const float4*>(&W1[(size_t)(base_k + k) * D + j]);
        sB[(j + 0) * 136 + k] = f2bf(v.x);
        sB[(j + 1) * 136 + k] = f2bf(v.y);
        sB[(j + 2) * 136 + k] = f2bf(v.z);
        sB[(j + 3) * 136 + k] = f2bf(v.w);
    }
    __syncthreads();

    const int wid = t >> 6, l = t & 63;
    const int m16 = l & 15, g4 = l >> 4;
    f32x4 acc[8];
    #pragma unroll
    for (int n = 0; n < 8; ++n) acc[n] = (f32x4){0.f, 0.f, 0.f, 0.f};

    #pragma unroll
    for (int kk = 0; kk < 4; ++kk) {
        int k0 = kk * 32 + g4 * 8;
        bf16x8 a = *reinterpret_cast<const bf16x8*>(&sA[(wid * 16 + m16) * 136 + k0]);
        #pragma unroll
        for (int n = 0; n < 8; ++n) {
            bf16x8 b = *reinterpret_cast<const bf16x8*>(&sB[(n * 16 + m16) * 136 + k0]);
            acc[n] = __builtin_amdgcn_mfma_f32_16x16x32_bf16(a, b, acc[n], 0, 0, 0);
        }
    }
    // C/D layout: col = lane&15, row = (lane>>4)*4 + r
    #pragma unroll
    for (int n = 0; n < 8; ++n) {
        #pragma unroll
        for (int r = 0; r < 4; ++r) {
            int row = r0 + wid * 16 + g4 * 4 + r;
            if (row < Nn) outbf[(size_t)row * D + n * 16 + m16] = f2bf(acc[n][r]);
        }
    }
}

// ---------------- K3: edge kernel. 16 lanes per edge, 4 edges per wave ----------------
__global__ __launch_bounds__(256) void edge_kernel(const unsigned short* __restrict__ A,
                                                   const unsigned short* __restrict__ B,
                                                   const int* __restrict__ src,
                                                   const int* __restrict__ dst,
                                                   const float* __restrict__ WcT,
                                                   float* __restrict__ out, int E) {
    const int l   = threadIdx.x & 63;
    const int sub = l & 15;          // lane within edge-group: owns k = sub*8 .. sub*8+7
    const int grp = l >> 4;          // which of 4 edges in this wave
    const int wave_gid = blockIdx.x * 4 + (threadIdx.x >> 6);
    const int nwaves = gridDim.x * 4;

    // Wc columns for this lane's k-slice, kept in registers (amortized over the loop)
    float4 wlo[5], whi[5];
    #pragma unroll
    for (int c = 0; c < 5; ++c) {
        wlo[c] = *reinterpret_cast<const float4*>(&WcT[c * 128 + sub * 8]);
        whi[c] = *reinterpret_cast<const float4*>(&WcT[c * 128 + sub * 8 + 4]);
    }

    const int Q = (E + 3) >> 2;
    for (int q = wave_gid; q < Q; q += nwaves) {
        int e = q * 4 + grp;
        bool ok = e < E;
        int ei = ok ? e : 0;
        int s = src[ei];
        int d = dst[ei];
        uint4 av = *reinterpret_cast<const uint4*>(&A[(size_t)s * 128 + sub * 8]);
        uint4 bv = *reinterpret_cast<const uint4*>(&B[(size_t)d * 128 + sub * 8]);

        float g[8];
        unsigned int aw[4] = {av.x, av.y, av.z, av.w};
        unsigned int bw[4] = {bv.x, bv.y, bv.z, bv.w};
        #pragma unroll
        for (int p = 0; p < 4; ++p) {
            float z0 = __uint_as_float(aw[p] << 16) + __uint_as_float(bw[p] << 16);
            float z1 = __uint_as_float(aw[p] & 0xffff0000u) + __uint_as_float(bw[p] & 0xffff0000u);
            g[2 * p]     = gelu_erf(z0);
            g[2 * p + 1] = gelu_erf(z1);
        }

        float acc[5];
        #pragma unroll
        for (int c = 0; c < 5; ++c) {
            acc[c] = g[0] * wlo[c].x + g[1] * wlo[c].y + g[2] * wlo[c].z + g[3] * wlo[c].w
                   + g[4] * whi[c].x + g[5] * whi[c].y + g[6] * whi[c].z + g[7] * whi[c].w;
        }
        // reduce across the 16 lanes of this edge (xor masks < 16 never cross the group)
        #pragma unroll
        for (int c = 0; c < 5; ++c) {
            float v = acc[c];
            v += __shfl_xor(v, 1);
            v += __shfl_xor(v, 2);
            v += __shfl_xor(v, 4);
            v += __shfl_xor(v, 8);
            acc[c] = v;
        }
        float v = acc[0];
        if (sub == 1) v = acc[1];
        if (sub == 2) v = acc[2];
        if (sub == 3) v = acc[3];
        if (sub == 4) v = acc[4];
        if (ok && sub < 5) out[(size_t)e * 5 + sub] = v;   // 20 contiguous floats per wave
    }
}

// ---------------- fallback (ws too small): fully fused per-edge ----------------
__global__ __launch_bounds__(256) void fused_fallback(const float* __restrict__ uf,
                                                      const float* __restrict__ vf,
                                                      const int* __restrict__ src,
                                                      const int* __restrict__ dst,
                                                      const float* __restrict__ W1,
                                                      const float* __restrict__ W2,
                                                      const float* __restrict__ Wp,
                                                      float* __restrict__ out, int E) {
    __shared__ unsigned short sW[256 * 128];  // bf16 W1[k][j]
    __shared__ float sWc[5 * 128];            // WcT[c][j]
    __shared__ float sH[4][256];
    const int t = threadIdx.x;
    #pragma unroll
    for (int i = 0; i < 32; ++i) {
        int f = (i * 256 + t) * 4;
        float4 v = *reinterpret_cast<const float4*>(&W1[f]);
        sW[f + 0] = f2bf(v.x); sW[f + 1] = f2bf(v.y);
        sW[f + 2] = f2bf(v.z); sW[f + 3] = f2bf(v.w);
    }
    for (int idx = t; idx < 640; idx += 256) {
        int c = idx >> 7, k = idx & 127;
        float a = 0.f;
        for (int m = 0; m < 128; ++m) a += W2[k * 128 + m] * Wp[m * 5 + c];
        sWc[c * 128 + k] = a;
    }
    __syncthreads();
    const int wid = t >> 6, l = t & 63;
    const int nw = gridDim.x * 4;
    for (int e = blockIdx.x * 4 + wid; e < E; e += nw) {
        int s = src[e], d0 = dst[e];
        float2 hu = *reinterpret_cast<const float2*>(&uf[(size_t)s * 128 + 2 * l]);
        float2 hv = *reinterpret_cast<const float2*>(&vf[(size_t)d0 * 128 + 2 * l]);
        sH[wid][2 * l] = hu.x; sH[wid][2 * l + 1] = hu.y;
        sH[wid][128 + 2 * l] = hv.x; sH[wid][128 + 2 * l + 1] = hv.y;
        __builtin_amdgcn_wave_barrier();
        float z0 = 0.f, z1 = 0.f;
        for (int k = 0; k < 256; ++k) {
            float h = sH[wid][k];
            z0 += h * bf2f(sW[k * 128 + l]);
            z1 += h * bf2f(sW[k * 128 + l + 64]);
        }
        float g0 = gelu_erf(z0), g1 = gelu_erf(z1);
        float acc[5];
        #pragma unroll
        for (int c = 0; c < 5; ++c)
            acc[c] = g0 * sWc[c * 128 + l] + g1 * sWc[c * 128 + l + 64];
        #pragma unroll
        for (int c = 0; c < 5; ++c) {
            float v = acc[c];
            v += __shfl_xor(v, 1);  v += __shfl_xor(v, 2);
            v += __shfl_xor(v, 4);  v += __shfl_xor(v, 8);
            v += __shfl_xor(v, 16); v += __shfl_xor(v, 32);
            acc[c] = v;
        }
        float v = acc[0];
        if (l == 1) v = acc[1];
        if (l == 2) v = acc[2];
        if (l == 3) v = acc[3];
        if (l == 4) v = acc[4];
        if (l < 5) out[(size_t)e * 5 + l] = v;
        __builtin_amdgcn_wave_barrier();
    }
}

extern "C" void kernel_launch(void* const* d_in, const int* in_sizes, int n_in,
                              void* d_out, int out_size, void* d_ws, size_t ws_size,
                              hipStream_t stream) {
    const float* ufeat = (const float*)d_in[0];
    const float* ifeat = (const float*)d_in[1];
    const int*   src   = (const int*)d_in[2];
    const int*   dst   = (const int*)d_in[3];
    const float* W1    = (const float*)d_in[4];
    const float* W2    = (const float*)d_in[5];
    const float* Wp    = (const float*)d_in[6];
    float* out = (float*)d_out;

    const int NU = in_sizes[0] / D;
    const int NM = in_sizes[1] / D;
    const int E  = in_sizes[2];

    size_t off_A = 4096;
    size_t szA = (size_t)NU * D * 2;
    size_t off_B = off_A + ((szA + 255) / 256) * 256;
    size_t need = off_B + (size_t)NM * D * 2;

    if (ws_size >= need) {
        float* WcT = (float*)d_ws;
        unsigned short* Abf = (unsigned short*)((char*)d_ws + off_A);
        unsigned short* Bbf = (unsigned short*)((char*)d_ws + off_B);
        wc_kernel<<<dim3(5), dim3(128), 0, stream>>>(W2, Wp, WcT);
        node_kernel<<<dim3((NU + 63) / 64), dim3(256), 0, stream>>>(ufeat, W1, 0, NU, Abf);
        node_kernel<<<dim3((NM + 63) / 64), dim3(256), 0, stream>>>(ifeat, W1, D, NM, Bbf);
        edge_kernel<<<dim3(4096), dim3(256), 0, stream>>>(Abf, Bbf, src, dst, WcT, out, E);
    } else {
        fused_fallback<<<dim3(4096), dim3(256), 0, stream>>>(ufeat, ifeat, src, dst,
                                                             W1, W2, Wp, out, E);
    }
}

// Round 2
// 115.153 us; speedup vs baseline: 1.5703x; 1.5703x over previous
//
#include <hip/hip_runtime.h>
#include <hip/hip_bf16.h>

#define D 128

typedef short bf16x8 __attribute__((ext_vector_type(8)));
typedef float f32x4 __attribute__((ext_vector_type(4)));

__device__ __forceinline__ unsigned short f2bf(float x) {
    __hip_bfloat16 h = __float2bfloat16(x);
    return *reinterpret_cast<unsigned short*>(&h);
}
__device__ __forceinline__ float bf2f(unsigned int lo16bits) {
    return __uint_as_float(lo16bits << 16);
}

// tanh-form GELU, algebraically reduced:
//   gelu(z) = 0.5 z (1 + tanh(c (z + 0.044715 z^3)))  = z * q/(1+q),  q = e^{2c(z+0.044715 z^3)}
//   q = exp2(z * (2.302264 + 0.1029466 z^2))   [2*c*log2e = 2.302264, *0.044715 = 0.1029466]
// Overflow-safe: q=inf -> rcp(1+inf)=0 -> gelu=z; q=0 -> gelu=0.
// Max deviation from exact erf-GELU ~5e-4 (negligible vs threshold).
__device__ __forceinline__ float gelu_tanh(float z) {
    float z2 = z * z;
    float xe = z * fmaf(0.1029466f, z2, 2.3022646f);
    float q  = __builtin_amdgcn_exp2f(xe);
    float r  = __builtin_amdgcn_rcpf(1.0f + q);
    return fmaf(-z, r, z);
}

// exact-ish GELU for the fallback path (erf via A&S 7.1.26)
__device__ __forceinline__ float gelu_erf(float z) {
    float y = fabsf(z) * 0.70710678118654752f;
    float t = __builtin_amdgcn_rcpf(1.0f + 0.3275911f * y);
    float poly = ((((1.061405429f * t - 1.453152027f) * t + 1.421413741f) * t
                   - 0.284496736f) * t + 0.254829592f) * t;
    float e = __expf(-y * y);
    float erfv = 1.0f - poly * e;
    erfv = copysignf(erfv, z);
    return 0.5f * z * (1.0f + erfv);
}

// ---------------- node transform body: out_bf16 = bf16(feat @ W1[base:base+128]) ----------------
__device__ __forceinline__ void node_body(const float* __restrict__ feat,
                                          const float* __restrict__ W1,
                                          int base_k, int Nn, int blk,
                                          unsigned short* __restrict__ outbf) {
    __shared__ unsigned short sA[64 * 136];    // sA[row][k], pad 8 -> conflict-free b128 reads
    __shared__ unsigned short sB[128 * 136];   // sB[j][k] = W1[base_k+k][j] (transposed)
    const int t = threadIdx.x;
    const int r0 = blk * 64;

    #pragma unroll
    for (int i = 0; i < 8; ++i) {
        int f = (i * 256 + t) * 4;
        int row = f >> 7, col = f & 127;
        float4 v = make_float4(0.f, 0.f, 0.f, 0.f);
        if (r0 + row < Nn) v = *reinterpret_cast<const float4*>(&feat[(size_t)(r0 + row) * D + col]);
        unsigned short* p = &sA[row * 136 + col];
        p[0] = f2bf(v.x); p[1] = f2bf(v.y); p[2] = f2bf(v.z); p[3] = f2bf(v.w);
    }
    #pragma unroll
    for (int i = 0; i < 16; ++i) {
        int f = (i * 256 + t) * 4;
        int k = f >> 7, j = f & 127;
        float4 v = *reinterpret_cast<const float4*>(&W1[(size_t)(base_k + k) * D + j]);
        sB[(j + 0) * 136 + k] = f2bf(v.x);
        sB[(j + 1) * 136 + k] = f2bf(v.y);
        sB[(j + 2) * 136 + k] = f2bf(v.z);
        sB[(j + 3) * 136 + k] = f2bf(v.w);
    }
    __syncthreads();

    const int wid = t >> 6, l = t & 63;
    const int m16 = l & 15, g4 = l >> 4;
    f32x4 acc[8];
    #pragma unroll
    for (int n = 0; n < 8; ++n) acc[n] = (f32x4){0.f, 0.f, 0.f, 0.f};

    #pragma unroll
    for (int kk = 0; kk < 4; ++kk) {
        int k0 = kk * 32 + g4 * 8;
        bf16x8 a = *reinterpret_cast<const bf16x8*>(&sA[(wid * 16 + m16) * 136 + k0]);
        #pragma unroll
        for (int n = 0; n < 8; ++n) {
            bf16x8 b = *reinterpret_cast<const bf16x8*>(&sB[(n * 16 + m16) * 136 + k0]);
            acc[n] = __builtin_amdgcn_mfma_f32_16x16x32_bf16(a, b, acc[n], 0, 0, 0);
        }
    }
    #pragma unroll
    for (int n = 0; n < 8; ++n) {
        #pragma unroll
        for (int r = 0; r < 4; ++r) {
            int row = r0 + wid * 16 + g4 * 4 + r;
            if (row < Nn) outbf[(size_t)row * D + n * 16 + m16] = f2bf(acc[n][r]);
        }
    }
}

// ---------------- prep: block-role split: u-tiles | i-tiles | Wc ----------------
__global__ __launch_bounds__(256) void prep_kernel(const float* __restrict__ uf,
                                                   const float* __restrict__ vf,
                                                   const float* __restrict__ W1,
                                                   const float* __restrict__ W2,
                                                   const float* __restrict__ Wp,
                                                   int NU, int NM, int nbU, int nbM,
                                                   unsigned short* __restrict__ Abf,
                                                   unsigned short* __restrict__ Bbf,
                                                   unsigned short* __restrict__ Wcbf) {
    int b = blockIdx.x;
    if (b < nbU) {
        node_body(uf, W1, 0, NU, b, Abf);
    } else if (b < nbU + nbM) {
        node_body(vf, W1, D, NM, b - nbU, Bbf);
    } else {
        // Wcbf[col][k] = bf16( sum_j W2[k][j] * Wp[j][col] ), cols 5..15 zero-padded
        int t = threadIdx.x;
        #pragma unroll
        for (int i = 0; i < 8; ++i) {
            int idx = i * 256 + t;
            int col = idx >> 7, k = idx & 127;
            float acc = 0.f;
            if (col < 5) {
                #pragma unroll 8
                for (int j = 0; j < D; ++j) acc += W2[k * D + j] * Wp[j * 5 + col];
            }
            Wcbf[col * D + k] = f2bf(acc);
        }
    }
}

// ---------------- edge kernel: 16 edges per wave, MFMA for the 128x5 dot ----------------
// Lane l: edge er=l&15 of the group, k-slice quad=(l>>4): k = kk*32 + quad*8 + j.
// Gathered+GELU'd bf16 values are exactly the 16x16x32 A-fragment; B-fragment is the
// loop-invariant Wc (col = l&15 = class, zero-padded to 16 cols).
// C: col = l&15 (class), row = quad*4+r (edge) -> 20 lanes store 4 floats each.
__global__ __launch_bounds__(256) void edge_kernel(const unsigned short* __restrict__ A,
                                                   const unsigned short* __restrict__ B,
                                                   const int* __restrict__ src,
                                                   const int* __restrict__ dst,
                                                   const unsigned short* __restrict__ Wcbf,
                                                   float* __restrict__ out, int E) {
    const int l    = threadIdx.x & 63;
    const int er   = l & 15;
    const int quad = l >> 4;
    const int wid  = blockIdx.x * 4 + (threadIdx.x >> 6);
    const int nw   = gridDim.x * 4;

    bf16x8 wfrag[4];
    #pragma unroll
    for (int kk = 0; kk < 4; ++kk)
        wfrag[kk] = *reinterpret_cast<const bf16x8*>(&Wcbf[er * D + kk * 32 + quad * 8]);

    const int Q = (E + 15) >> 4;
    if (wid >= Q) return;

    // prefetch first indices
    int q0 = wid;
    int s = src[q0 * 16 + er];
    int d = dst[q0 * 16 + er];

    for (int q = q0; q < Q; q += nw) {
        // prefetch next iteration's indices (hide idx->gather chain)
        int qn = q + nw;
        int qc = qn < Q ? qn : q;
        int sn = src[qc * 16 + er];
        int dn = dst[qc * 16 + er];

        const unsigned short* ap = A + ((size_t)s << 7) + quad * 8;
        const unsigned short* bp = B + ((size_t)d << 7) + quad * 8;
        uint4 av[4], bv[4];
        #pragma unroll
        for (int kk = 0; kk < 4; ++kk) {
            av[kk] = *reinterpret_cast<const uint4*>(ap + kk * 32);
            bv[kk] = *reinterpret_cast<const uint4*>(bp + kk * 32);
        }

        f32x4 acc = (f32x4){0.f, 0.f, 0.f, 0.f};
        #pragma unroll
        for (int kk = 0; kk < 4; ++kk) {
            unsigned int aw[4] = {av[kk].x, av[kk].y, av[kk].z, av[kk].w};
            unsigned int bw[4] = {bv[kk].x, bv[kk].y, bv[kk].z, bv[kk].w};
            union { bf16x8 v; unsigned short u[8]; } frag;
            #pragma unroll
            for (int p = 0; p < 4; ++p) {
                float z0 = __uint_as_float(aw[p] << 16) + __uint_as_float(bw[p] << 16);
                float z1 = __uint_as_float(aw[p] & 0xffff0000u) + __uint_as_float(bw[p] & 0xffff0000u);
                frag.u[2 * p]     = f2bf(gelu_tanh(z0));
                frag.u[2 * p + 1] = f2bf(gelu_tanh(z1));
            }
            acc = __builtin_amdgcn_mfma_f32_16x16x32_bf16(frag.v, wfrag[kk], acc, 0, 0, 0);
        }

        int e0 = q << 4;
        #pragma unroll
        for (int r = 0; r < 4; ++r) {
            int e = e0 + quad * 4 + r;
            if (er < 5 && e < E) out[(size_t)e * 5 + er] = acc[r];
        }
        s = sn; d = dn;
    }
}

// ---------------- fallback (ws too small): fully fused per-edge ----------------
__global__ __launch_bounds__(256) void fused_fallback(const float* __restrict__ uf,
                                                      const float* __restrict__ vf,
                                                      const int* __restrict__ src,
                                                      const int* __restrict__ dst,
                                                      const float* __restrict__ W1,
                                                      const float* __restrict__ W2,
                                                      const float* __restrict__ Wp,
                                                      float* __restrict__ out, int E) {
    __shared__ unsigned short sW[256 * 128];
    __shared__ float sWc[5 * 128];
    __shared__ float sH[4][256];
    const int t = threadIdx.x;
    #pragma unroll
    for (int i = 0; i < 32; ++i) {
        int f = (i * 256 + t) * 4;
        float4 v = *reinterpret_cast<const float4*>(&W1[f]);
        sW[f + 0] = f2bf(v.x); sW[f + 1] = f2bf(v.y);
        sW[f + 2] = f2bf(v.z); sW[f + 3] = f2bf(v.w);
    }
    for (int idx = t; idx < 640; idx += 256) {
        int c = idx >> 7, k = idx & 127;
        float a = 0.f;
        for (int m = 0; m < 128; ++m) a += W2[k * 128 + m] * Wp[m * 5 + c];
        sWc[c * 128 + k] = a;
    }
    __syncthreads();
    const int wid = t >> 6, l = t & 63;
    const int nw = gridDim.x * 4;
    for (int e = blockIdx.x * 4 + wid; e < E; e += nw) {
        int s = src[e], d0 = dst[e];
        float2 hu = *reinterpret_cast<const float2*>(&uf[(size_t)s * 128 + 2 * l]);
        float2 hv = *reinterpret_cast<const float2*>(&vf[(size_t)d0 * 128 + 2 * l]);
        sH[wid][2 * l] = hu.x; sH[wid][2 * l + 1] = hu.y;
        sH[wid][128 + 2 * l] = hv.x; sH[wid][128 + 2 * l + 1] = hv.y;
        __builtin_amdgcn_wave_barrier();
        float z0 = 0.f, z1 = 0.f;
        for (int k = 0; k < 256; ++k) {
            float h = sH[wid][k];
            z0 += h * bf2f(sW[k * 128 + l]);
            z1 += h * bf2f(sW[k * 128 + l + 64]);
        }
        float g0 = gelu_erf(z0), g1 = gelu_erf(z1);
        float acc[5];
        #pragma unroll
        for (int c = 0; c < 5; ++c)
            acc[c] = g0 * sWc[c * 128 + l] + g1 * sWc[c * 128 + l + 64];
        #pragma unroll
        for (int c = 0; c < 5; ++c) {
            float v = acc[c];
            v += __shfl_xor(v, 1);  v += __shfl_xor(v, 2);
            v += __shfl_xor(v, 4);  v += __shfl_xor(v, 8);
            v += __shfl_xor(v, 16); v += __shfl_xor(v, 32);
            acc[c] = v;
        }
        float v = acc[0];
        if (l == 1) v = acc[1];
        if (l == 2) v = acc[2];
        if (l == 3) v = acc[3];
        if (l == 4) v = acc[4];
        if (l < 5) out[(size_t)e * 5 + l] = v;
        __builtin_amdgcn_wave_barrier();
    }
}

extern "C" void kernel_launch(void* const* d_in, const int* in_sizes, int n_in,
                              void* d_out, int out_size, void* d_ws, size_t ws_size,
                              hipStream_t stream) {
    const float* ufeat = (const float*)d_in[0];
    const float* ifeat = (const float*)d_in[1];
    const int*   src   = (const int*)d_in[2];
    const int*   dst   = (const int*)d_in[3];
    const float* W1    = (const float*)d_in[4];
    const float* W2    = (const float*)d_in[5];
    const float* Wp    = (const float*)d_in[6];
    float* out = (float*)d_out;

    const int NU = in_sizes[0] / D;
    const int NM = in_sizes[1] / D;
    const int E  = in_sizes[2];

    size_t off_A = 4096;                               // Wcbf16 lives at [0, 4KB)
    size_t szA = (size_t)NU * D * 2;
    size_t off_B = off_A + ((szA + 255) / 256) * 256;
    size_t need = off_B + (size_t)NM * D * 2;

    if (ws_size >= need) {
        unsigned short* Wcbf = (unsigned short*)d_ws;
        unsigned short* Abf  = (unsigned short*)((char*)d_ws + off_A);
        unsigned short* Bbf  = (unsigned short*)((char*)d_ws + off_B);
        int nbU = (NU + 63) / 64, nbM = (NM + 63) / 64;
        prep_kernel<<<dim3(nbU + nbM + 1), dim3(256), 0, stream>>>(
            ufeat, ifeat, W1, W2, Wp, NU, NM, nbU, nbM, Abf, Bbf, Wcbf);
        edge_kernel<<<dim3(2048), dim3(256), 0, stream>>>(Abf, Bbf, src, dst, Wcbf, out, E);
    } else {
        fused_fallback<<<dim3(4096), dim3(256), 0, stream>>>(ufeat, ifeat, src, dst,
                                                             W1, W2, Wp, out, E);
    }
}

// Round 3
// 113.911 us; speedup vs baseline: 1.5874x; 1.0109x over previous
//
#include <hip/hip_runtime.h>
#include <hip/hip_bf16.h>

#define D 128

typedef short bf16x8 __attribute__((ext_vector_type(8)));
typedef float f32x4 __attribute__((ext_vector_type(4)));
typedef float f32x2 __attribute__((ext_vector_type(2)));

__device__ __forceinline__ unsigned short f2bf(float x) {
    __hip_bfloat16 h = __float2bfloat16(x);
    return *reinterpret_cast<unsigned short*>(&h);
}
__device__ __forceinline__ float bflo(unsigned int w) { return __uint_as_float(w << 16); }
__device__ __forceinline__ float bfhi(unsigned int w) { return __uint_as_float(w & 0xffff0000u); }

// tanh-form GELU on a packed pair:
//   gelu(z) = z - z/(1+q),  q = exp2(z*(2.3022646 + 0.1029466 z^2))
// Overflow-safe (q=inf -> rcp=0 -> gelu=z). |err vs exact erf-GELU| ~5e-4.
__device__ __forceinline__ f32x2 gelu2(f32x2 z) {
    f32x2 z2 = z * z;
    f32x2 c1 = {0.1029466f, 0.1029466f};
    f32x2 c0 = {2.3022646f, 2.3022646f};
    f32x2 xe = z * __builtin_elementwise_fma(z2, c1, c0);
    f32x2 q;
    q.x = __builtin_amdgcn_exp2f(xe.x);
    q.y = __builtin_amdgcn_exp2f(xe.y);
    f32x2 d = q + 1.0f;
    f32x2 r;
    r.x = __builtin_amdgcn_rcpf(d.x);
    r.y = __builtin_amdgcn_rcpf(d.y);
    return __builtin_elementwise_fma(-z, r, z);
}

// exact-ish GELU for the fallback path (erf via A&S 7.1.26)
__device__ __forceinline__ float gelu_erf(float z) {
    float y = fabsf(z) * 0.70710678118654752f;
    float t = __builtin_amdgcn_rcpf(1.0f + 0.3275911f * y);
    float poly = ((((1.061405429f * t - 1.453152027f) * t + 1.421413741f) * t
                   - 0.284496736f) * t + 0.254829592f) * t;
    float e = __expf(-y * y);
    float erfv = 1.0f - poly * e;
    erfv = copysignf(erfv, z);
    return 0.5f * z * (1.0f + erfv);
}

// ---------------- node transform: out_bf16 = bf16(feat @ W1[base:base+128]) ----------------
// A-fragments read straight from global (no LDS staging); W1 (transposed) staged in LDS.
__device__ __forceinline__ void node_body(const float* __restrict__ feat,
                                          const float* __restrict__ W1,
                                          int base_k, int Nn, int blk,
                                          unsigned short* __restrict__ outbf) {
    __shared__ unsigned short sB[128 * 136];   // sB[j][k] = W1[base_k+k][j], pad 8
    const int t = threadIdx.x;
    const int r0 = blk * 64;

    #pragma unroll
    for (int i = 0; i < 16; ++i) {
        int f = (i * 256 + t) * 4;
        int k = f >> 7, j = f & 127;
        float4 v = *reinterpret_cast<const float4*>(&W1[(size_t)(base_k + k) * D + j]);
        sB[(j + 0) * 136 + k] = f2bf(v.x);
        sB[(j + 1) * 136 + k] = f2bf(v.y);
        sB[(j + 2) * 136 + k] = f2bf(v.z);
        sB[(j + 3) * 136 + k] = f2bf(v.w);
    }
    __syncthreads();

    const int wid = t >> 6, l = t & 63;
    const int m16 = l & 15, g4 = l >> 4;
    const int arow = r0 + wid * 16 + m16;
    const bool rok = arow < Nn;
    const float* rp = feat + (size_t)(rok ? arow : 0) * D;

    f32x4 acc[8];
    #pragma unroll
    for (int n = 0; n < 8; ++n) acc[n] = (f32x4){0.f, 0.f, 0.f, 0.f};

    #pragma unroll
    for (int kk = 0; kk < 4; ++kk) {
        int k0 = kk * 32 + g4 * 8;
        float4 f0 = make_float4(0.f, 0.f, 0.f, 0.f), f1 = f0;
        if (rok) {
            f0 = *reinterpret_cast<const float4*>(rp + k0);
            f1 = *reinterpret_cast<const float4*>(rp + k0 + 4);
        }
        union { bf16x8 v; unsigned short u[8]; } a;
        a.u[0] = f2bf(f0.x); a.u[1] = f2bf(f0.y); a.u[2] = f2bf(f0.z); a.u[3] = f2bf(f0.w);
        a.u[4] = f2bf(f1.x); a.u[5] = f2bf(f1.y); a.u[6] = f2bf(f1.z); a.u[7] = f2bf(f1.w);
        #pragma unroll
        for (int n = 0; n < 8; ++n) {
            bf16x8 b = *reinterpret_cast<const bf16x8*>(&sB[(n * 16 + m16) * 136 + k0]);
            acc[n] = __builtin_amdgcn_mfma_f32_16x16x32_bf16(a.v, b, acc[n], 0, 0, 0);
        }
    }
    #pragma unroll
    for (int n = 0; n < 8; ++n) {
        #pragma unroll
        for (int r = 0; r < 4; ++r) {
            int row = r0 + wid * 16 + g4 * 4 + r;
            if (row < Nn) outbf[(size_t)row * D + n * 16 + m16] = f2bf(acc[n][r]);
        }
    }
}

// ---------------- prep: block-role split: u-tiles | i-tiles | Wc ----------------
__global__ __launch_bounds__(256) void prep_kernel(const float* __restrict__ uf,
                                                   const float* __restrict__ vf,
                                                   const float* __restrict__ W1,
                                                   const float* __restrict__ W2,
                                                   const float* __restrict__ Wp,
                                                   int NU, int NM, int nbU, int nbM,
                                                   unsigned short* __restrict__ Abf,
                                                   unsigned short* __restrict__ Bbf,
                                                   unsigned short* __restrict__ Wcbf) {
    int b = blockIdx.x;
    if (b < nbU) {
        node_body(uf, W1, 0, NU, b, Abf);
    } else if (b < nbU + nbM) {
        node_body(vf, W1, D, NM, b - nbU, Bbf);
    } else {
        int t = threadIdx.x;
        #pragma unroll
        for (int i = 0; i < 8; ++i) {
            int idx = i * 256 + t;
            int col = idx >> 7, k = idx & 127;
            float acc = 0.f;
            if (col < 5) {
                #pragma unroll 8
                for (int j = 0; j < D; ++j) acc += W2[k * D + j] * Wp[j * 5 + col];
            }
            Wcbf[col * D + k] = f2bf(acc);
        }
    }
}

// ---------------- edge kernel: 32 edges (2 MFMA groups) per wave-iter ----------------
// Lane l: edge er=l&15 within group, k-slice quad=l>>4 (k = kk*32 + quad*8 + j).
// B-fragment = loop-invariant Wc (col = er = class, zero-padded to 16 cols).
// C: col=l&15 (class), row=quad*4+r (edge).
__global__ __launch_bounds__(256, 4) void edge_kernel(const unsigned short* __restrict__ A,
                                                      const unsigned short* __restrict__ B,
                                                      const int* __restrict__ src,
                                                      const int* __restrict__ dst,
                                                      const unsigned short* __restrict__ Wcbf,
                                                      float* __restrict__ out, int E) {
    const int l    = threadIdx.x & 63;
    const int er   = l & 15;
    const int quad = l >> 4;
    const int wid  = blockIdx.x * 4 + (threadIdx.x >> 6);
    const int nw   = gridDim.x * 4;

    bf16x8 wfrag[4];
    #pragma unroll
    for (int kk = 0; kk < 4; ++kk)
        wfrag[kk] = *reinterpret_cast<const bf16x8*>(&Wcbf[er * D + kk * 32 + quad * 8]);

    const int P = (E + 31) >> 5;   // pairs of 16-edge groups
    if (wid >= P) return;
    const int Emax = E - 1;

    // prefetch first indices (both groups)
    int ia = wid * 32 + er, ib = ia + 16;
    int sa = src[min(ia, Emax)], da = dst[min(ia, Emax)];
    int sb = src[min(ib, Emax)], db = dst[min(ib, Emax)];

    for (int p = wid; p < P; p += nw) {
        // prefetch next iteration's indices
        int pn = p + nw;
        int pc = pn < P ? pn : p;
        int ja = pc * 32 + er, jb = ja + 16;
        int san = src[min(ja, Emax)], dan = dst[min(ja, Emax)];
        int sbn = src[min(jb, Emax)], dbn = dst[min(jb, Emax)];

        const unsigned short* apA = A + ((size_t)sa << 7) + quad * 8;
        const unsigned short* bpA = B + ((size_t)da << 7) + quad * 8;
        const unsigned short* apB = A + ((size_t)sb << 7) + quad * 8;
        const unsigned short* bpB = B + ((size_t)db << 7) + quad * 8;
        uint4 a0[4], b0[4], a1[4], b1[4];
        #pragma unroll
        for (int kk = 0; kk < 4; ++kk) {
            a0[kk] = *reinterpret_cast<const uint4*>(apA + kk * 32);
            b0[kk] = *reinterpret_cast<const uint4*>(bpA + kk * 32);
            a1[kk] = *reinterpret_cast<const uint4*>(apB + kk * 32);
            b1[kk] = *reinterpret_cast<const uint4*>(bpB + kk * 32);
        }

        f32x4 accA = (f32x4){0.f, 0.f, 0.f, 0.f};
        f32x4 accB = accA;
        #pragma unroll
        for (int kk = 0; kk < 4; ++kk) {
            unsigned int aw[4] = {a0[kk].x, a0[kk].y, a0[kk].z, a0[kk].w};
            unsigned int bw[4] = {b0[kk].x, b0[kk].y, b0[kk].z, b0[kk].w};
            union { bf16x8 v; unsigned short u[8]; } frag;
            #pragma unroll
            for (int pp = 0; pp < 4; ++pp) {
                f32x2 za = {bflo(aw[pp]), bfhi(aw[pp])};
                f32x2 zb = {bflo(bw[pp]), bfhi(bw[pp])};
                f32x2 g = gelu2(za + zb);
                frag.u[2 * pp]     = f2bf(g.x);
                frag.u[2 * pp + 1] = f2bf(g.y);
            }
            accA = __builtin_amdgcn_mfma_f32_16x16x32_bf16(frag.v, wfrag[kk], accA, 0, 0, 0);
        }
        #pragma unroll
        for (int kk = 0; kk < 4; ++kk) {
            unsigned int aw[4] = {a1[kk].x, a1[kk].y, a1[kk].z, a1[kk].w};
            unsigned int bw[4] = {b1[kk].x, b1[kk].y, b1[kk].z, b1[kk].w};
            union { bf16x8 v; unsigned short u[8]; } frag;
            #pragma unroll
            for (int pp = 0; pp < 4; ++pp) {
                f32x2 za = {bflo(aw[pp]), bfhi(aw[pp])};
                f32x2 zb = {bflo(bw[pp]), bfhi(bw[pp])};
                f32x2 g = gelu2(za + zb);
                frag.u[2 * pp]     = f2bf(g.x);
                frag.u[2 * pp + 1] = f2bf(g.y);
            }
            accB = __builtin_amdgcn_mfma_f32_16x16x32_bf16(frag.v, wfrag[kk], accB, 0, 0, 0);
        }

        int e0 = p << 5;
        #pragma unroll
        for (int r = 0; r < 4; ++r) {
            int eA = e0 + quad * 4 + r;
            if (er < 5 && eA < E) out[(size_t)eA * 5 + er] = accA[r];
        }
        #pragma unroll
        for (int r = 0; r < 4; ++r) {
            int eB = e0 + 16 + quad * 4 + r;
            if (er < 5 && eB < E) out[(size_t)eB * 5 + er] = accB[r];
        }
        sa = san; da = dan; sb = sbn; db = dbn;
    }
}

// ---------------- fallback (ws too small): fully fused per-edge ----------------
__global__ __launch_bounds__(256) void fused_fallback(const float* __restrict__ uf,
                                                      const float* __restrict__ vf,
                                                      const int* __restrict__ src,
                                                      const int* __restrict__ dst,
                                                      const float* __restrict__ W1,
                                                      const float* __restrict__ W2,
                                                      const float* __restrict__ Wp,
                                                      float* __restrict__ out, int E) {
    __shared__ unsigned short sW[256 * 128];
    __shared__ float sWc[5 * 128];
    __shared__ float sH[4][256];
    const int t = threadIdx.x;
    #pragma unroll
    for (int i = 0; i < 32; ++i) {
        int f = (i * 256 + t) * 4;
        float4 v = *reinterpret_cast<const float4*>(&W1[f]);
        sW[f + 0] = f2bf(v.x); sW[f + 1] = f2bf(v.y);
        sW[f + 2] = f2bf(v.z); sW[f + 3] = f2bf(v.w);
    }
    for (int idx = t; idx < 640; idx += 256) {
        int c = idx >> 7, k = idx & 127;
        float a = 0.f;
        for (int m = 0; m < 128; ++m) a += W2[k * 128 + m] * Wp[m * 5 + c];
        sWc[c * 128 + k] = a;
    }
    __syncthreads();
    const int wid = t >> 6, l = t & 63;
    const int nw = gridDim.x * 4;
    for (int e = blockIdx.x * 4 + wid; e < E; e += nw) {
        int s = src[e], d0 = dst[e];
        float2 hu = *reinterpret_cast<const float2*>(&uf[(size_t)s * 128 + 2 * l]);
        float2 hv = *reinterpret_cast<const float2*>(&vf[(size_t)d0 * 128 + 2 * l]);
        sH[wid][2 * l] = hu.x; sH[wid][2 * l + 1] = hu.y;
        sH[wid][128 + 2 * l] = hv.x; sH[wid][128 + 2 * l + 1] = hv.y;
        __builtin_amdgcn_wave_barrier();
        float z0 = 0.f, z1 = 0.f;
        for (int k = 0; k < 256; ++k) {
            float h = sH[wid][k];
            z0 += h * __uint_as_float((unsigned int)sW[k * 128 + l] << 16);
            z1 += h * __uint_as_float((unsigned int)sW[k * 128 + l + 64] << 16);
        }
        float g0 = gelu_erf(z0), g1 = gelu_erf(z1);
        float acc[5];
        #pragma unroll
        for (int c = 0; c < 5; ++c)
            acc[c] = g0 * sWc[c * 128 + l] + g1 * sWc[c * 128 + l + 64];
        #pragma unroll
        for (int c = 0; c < 5; ++c) {
            float v = acc[c];
            v += __shfl_xor(v, 1);  v += __shfl_xor(v, 2);
            v += __shfl_xor(v, 4);  v += __shfl_xor(v, 8);
            v += __shfl_xor(v, 16); v += __shfl_xor(v, 32);
            acc[c] = v;
        }
        float v = acc[0];
        if (l == 1) v = acc[1];
        if (l == 2) v = acc[2];
        if (l == 3) v = acc[3];
        if (l == 4) v = acc[4];
        if (l < 5) out[(size_t)e * 5 + l] = v;
        __builtin_amdgcn_wave_barrier();
    }
}

extern "C" void kernel_launch(void* const* d_in, const int* in_sizes, int n_in,
                              void* d_out, int out_size, void* d_ws, size_t ws_size,
                              hipStream_t stream) {
    const float* ufeat = (const float*)d_in[0];
    const float* ifeat = (const float*)d_in[1];
    const int*   src   = (const int*)d_in[2];
    const int*   dst   = (const int*)d_in[3];
    const float* W1    = (const float*)d_in[4];
    const float* W2    = (const float*)d_in[5];
    const float* Wp    = (const float*)d_in[6];
    float* out = (float*)d_out;

    const int NU = in_sizes[0] / D;
    const int NM = in_sizes[1] / D;
    const int E  = in_sizes[2];

    size_t off_A = 4096;                               // Wcbf16 lives at [0, 4KB)
    size_t szA = (size_t)NU * D * 2;
    size_t off_B = off_A + ((szA + 255) / 256) * 256;
    size_t need = off_B + (size_t)NM * D * 2;

    if (ws_size >= need) {
        unsigned short* Wcbf = (unsigned short*)d_ws;
        unsigned short* Abf  = (unsigned short*)((char*)d_ws + off_A);
        unsigned short* Bbf  = (unsigned short*)((char*)d_ws + off_B);
        int nbU = (NU + 63) / 64, nbM = (NM + 63) / 64;
        prep_kernel<<<dim3(nbU + nbM + 1), dim3(256), 0, stream>>>(
            ufeat, ifeat, W1, W2, Wp, NU, NM, nbU, nbM, Abf, Bbf, Wcbf);
        int P = (E + 31) >> 5;
        int blocks = (P + 3) / 4; if (blocks > 2048) blocks = 2048;
        edge_kernel<<<dim3(blocks), dim3(256), 0, stream>>>(Abf, Bbf, src, dst, Wcbf, out, E);
    } else {
        fused_fallback<<<dim3(4096), dim3(256), 0, stream>>>(ufeat, ifeat, src, dst,
                                                             W1, W2, Wp, out, E);
    }
}